// Round 3
// baseline (723.357 us; speedup 1.0000x reference)
//
#include <hip/hip_runtime.h>

// ---------------- constants ----------------
#define B_ 4
#define Hh_ 32
#define Ww_ 32
#define L_ 1024
#define HID_ 512
#define DI_ 1024
#define N_ 64
#define R_ 32
#define K_ 4
#define MLP_ 2048

typedef __bf16 bf16x8 __attribute__((ext_vector_type(8)));
typedef float f32x4 __attribute__((ext_vector_type(4)));

__device__ __forceinline__ unsigned short f2bf(float f) {
  unsigned int u = __builtin_bit_cast(unsigned int, f);
  return (unsigned short)((u + 0x7FFFu + ((u >> 16) & 1u)) >> 16);
}

// ---------------- transpose + cast weights: src (K,N) f32 -> dst (N,K) bf16 ----------------
__global__ __launch_bounds__(256) void transpose_cast(
    const float* __restrict__ src, unsigned short* __restrict__ dst, int K, int N) {
  __shared__ float t[32][33];
  int nb = blockIdx.x * 32, kb = blockIdx.y * 32;
  int tx = threadIdx.x & 31, ty = threadIdx.x >> 5;
  for (int r = ty; r < 32; r += 8) t[r][tx] = src[(size_t)(kb + r) * N + nb + tx];
  __syncthreads();
  for (int r = ty; r < 32; r += 8) dst[(size_t)(nb + r) * K + kb + tx] = f2bf(t[tx][r]);
}

// ---------------- LayerNorm over 512, wave per row ----------------
__global__ __launch_bounds__(256) void ln_kernel(
    const float* __restrict__ in, float* __restrict__ out,
    const float* __restrict__ w, const float* __restrict__ bb) {
  int row = blockIdx.x * 4 + (threadIdx.x >> 6);
  int lane = threadIdx.x & 63;
  const float* p = in + (size_t)row * HID_;
  float4 v0 = *(const float4*)(p + lane * 4);
  float4 v1 = *(const float4*)(p + 256 + lane * 4);
  float s = v0.x + v0.y + v0.z + v0.w + v1.x + v1.y + v1.z + v1.w;
  float q = v0.x * v0.x + v0.y * v0.y + v0.z * v0.z + v0.w * v0.w +
            v1.x * v1.x + v1.y * v1.y + v1.z * v1.z + v1.w * v1.w;
  #pragma unroll
  for (int m = 1; m < 64; m <<= 1) { s += __shfl_xor(s, m, 64); q += __shfl_xor(q, m, 64); }
  float mean = s * (1.f / 512.f);
  float var = q * (1.f / 512.f) - mean * mean;
  float rstd = rsqrtf(var + 1e-5f);
  float4 w0 = *(const float4*)(w + lane * 4);
  float4 w1 = *(const float4*)(w + 256 + lane * 4);
  float4 b0 = *(const float4*)(bb + lane * 4);
  float4 b1 = *(const float4*)(bb + 256 + lane * 4);
  float* o = out + (size_t)row * HID_;
  float4 r0, r1;
  r0.x = (v0.x - mean) * rstd * w0.x + b0.x;
  r0.y = (v0.y - mean) * rstd * w0.y + b0.y;
  r0.z = (v0.z - mean) * rstd * w0.z + b0.z;
  r0.w = (v0.w - mean) * rstd * w0.w + b0.w;
  r1.x = (v1.x - mean) * rstd * w1.x + b1.x;
  r1.y = (v1.y - mean) * rstd * w1.y + b1.y;
  r1.z = (v1.z - mean) * rstd * w1.z + b1.z;
  r1.w = (v1.w - mean) * rstd * w1.w + b1.w;
  *(float4*)(o + lane * 4) = r0;
  *(float4*)(o + 256 + lane * 4) = r1;
}

// ---------------- MFMA GEMM: A (M,K) f32, BT (N,K) bf16, C (M,N) f32 ----------------
// EPI: 0 = plain, 1 = +resid, 2 = +bias then exact gelu, 3 = +bias +resid
#define BM 128
#define BN 128
#define BK 32
#define LST 40  // LDS row stride in bf16 units (80B, 16B-aligned, conflict-light)

template <int EPI>
__global__ __launch_bounds__(256) void gemm_kernel(
    const float* __restrict__ A, const unsigned short* __restrict__ BT,
    float* __restrict__ C, int M, int N, int K,
    const float* __restrict__ bias, const float* __restrict__ resid) {
  __shared__ __align__(16) unsigned short As[BM * LST];
  __shared__ __align__(16) unsigned short Bs[BN * LST];
  int tid = threadIdx.x;
  int lane = tid & 63, wv = tid >> 6;
  int wm = wv >> 1, wn = wv & 1;
  int m0 = blockIdx.y * BM, n0 = blockIdx.x * BN;
  f32x4 acc[4][4] = {};
  int sr = tid >> 3, sc = (tid & 7) * 4;
  int kk = (lane >> 4) * 8;
  int rA = wm * 64 + (lane & 15);
  int rB = wn * 64 + (lane & 15);
  for (int k0 = 0; k0 < K; k0 += BK) {
    __syncthreads();
    #pragma unroll
    for (int p = 0; p < 4; ++p) {
      int r = sr + p * 32;
      float4 av = *(const float4*)(A + (size_t)(m0 + r) * K + k0 + sc);
      unsigned int lo = (unsigned int)f2bf(av.x) | ((unsigned int)f2bf(av.y) << 16);
      unsigned int hi = (unsigned int)f2bf(av.z) | ((unsigned int)f2bf(av.w) << 16);
      *(uint2*)&As[r * LST + sc] = make_uint2(lo, hi);
      uint2 bv = *(const uint2*)(BT + (size_t)(n0 + r) * K + k0 + sc);
      *(uint2*)&Bs[r * LST + sc] = bv;
    }
    __syncthreads();
    bf16x8 fa[4], fb[4];
    #pragma unroll
    for (int i = 0; i < 4; ++i) {
      fa[i] = *(const bf16x8*)&As[(rA + i * 16) * LST + kk];
      fb[i] = *(const bf16x8*)&Bs[(rB + i * 16) * LST + kk];
    }
    #pragma unroll
    for (int i = 0; i < 4; ++i)
      #pragma unroll
      for (int j = 0; j < 4; ++j)
        acc[i][j] = __builtin_amdgcn_mfma_f32_16x16x32_bf16(fa[i], fb[j], acc[i][j], 0, 0, 0);
  }
  int crow0 = m0 + wm * 64 + (lane >> 4) * 4, ccol0 = n0 + wn * 64 + (lane & 15);
  #pragma unroll
  for (int i = 0; i < 4; ++i) {
    #pragma unroll
    for (int j = 0; j < 4; ++j) {
      int col = ccol0 + j * 16;
      #pragma unroll
      for (int r = 0; r < 4; ++r) {
        int row = crow0 + i * 16 + r;
        float v = acc[i][j][r];
        if (EPI == 1) v += resid[(size_t)row * N + col];
        if (EPI == 2) { v += bias[col]; v = 0.5f * v * (1.f + erff(v * 0.70710678f)); }
        if (EPI == 3) v += bias[col] + resid[(size_t)row * N + col];
        C[(size_t)row * N + col] = v;
      }
    }
  }
}

// ---------------- depthwise 3x3 conv + bias + SiLU (channels-last) ----------------
__global__ __launch_bounds__(256) void conv_kernel(
    const float* __restrict__ xz, const float* __restrict__ cw,
    const float* __restrict__ cb, float* __restrict__ xa) {
  int idx = blockIdx.x * 256 + threadIdx.x;  // (b,l,d), d fastest
  int d = idx & (DI_ - 1);
  int l = (idx >> 10) & (L_ - 1);
  int b = idx >> 20;
  int hh = l >> 5, ww = l & 31;
  float acc = cb[d];
  #pragma unroll
  for (int dh = -1; dh <= 1; ++dh) {
    int y = hh + dh;
    if ((unsigned)y >= 32u) continue;
    #pragma unroll
    for (int dw = -1; dw <= 1; ++dw) {
      int x = ww + dw;
      if ((unsigned)x >= 32u) continue;
      acc = fmaf(xz[((size_t)b * L_ + y * 32 + x) * (2 * DI_) + d],
                 cw[d * 9 + (dh + 1) * 3 + (dw + 1)], acc);
    }
  }
  float sv = acc / (1.f + __expf(-acc));
  xa[idx] = sv;
}

// ---------------- selective scan with fused dt-projection ----------------
// Lane layout: dg = lane&3 (4 d per wave), ng = lane>>2 (16 n-groups of 4 n).
// Block: 512 threads = 8 waves = 32 d. Grid: (DI/32, K, B) = 512 blocks.
// delta computed in-kernel: softplus(rank(32) . dtw + bias), one thread per (l,d) per chunk.
#define CH 16
#define NCH (L_ / CH)
__global__ __launch_bounds__(512) void scan_kernel(
    float* __restrict__ ybuf, const float* __restrict__ xa,
    const float* __restrict__ sp, const float* __restrict__ Cs,
    const float* __restrict__ A_logs, const float* __restrict__ Ds,
    const float* __restrict__ dtw, const float* __restrict__ dtb) {
  int dblk = blockIdx.x;  // 32 blocks of 32 d's
  int k = blockIdx.y, b = blockIdx.z;
  int tid = threadIdx.x, lane = tid & 63, wv = tid >> 6;
  int dg = lane & 3, ng = lane >> 2;
  int wd = wv * 4 + dg;                // d within block's 32
  int gd = k * DI_ + dblk * 32 + wd;
  float a2[4], h[4];
  #pragma unroll
  for (int j = 0; j < 4; ++j) {
    a2[j] = -__expf(A_logs[(size_t)gd * N_ + ng * 4 + j]) * 1.44269504f;
    h[j] = 0.f;
  }
  float dsv = Ds[gd];

  __shared__ float Bsh[2][CH][64], Csh[2][CH][64];
  __shared__ float Ush[2][CH][32], Rsh[2][CH][32], DLsh[2][CH][32];
  __shared__ float Wsh[32][32];
  __shared__ float yl[CH][32];

  const size_t spB = (size_t)b * L_ * 384 + 128 + k * 64;  // B part
  const size_t spR = (size_t)b * L_ * 384 + k * 32;        // rank part
  const size_t csB = (size_t)b * L_ * 256 + k * 64;
  const size_t yB  = ((size_t)(b * 4 + k) * L_) * DI_ + dblk * 32;
  const size_t xaB = (size_t)b * L_ * DI_ + dblk * 32;

  // stage dt weight slice: Wsh[r][dd] = dtw[(k*DI + dblk*32 + dd)*32 + r]
  for (int i = tid; i < 1024; i += 512) {
    int dd = i >> 5, r = i & 31;
    Wsh[r][dd] = dtw[((size_t)k * DI_ + dblk * 32 + dd) * R_ + r];
  }
  float biasv = dtb[k * DI_ + dblk * 32 + (tid & 31)];

  // staging roles (wave-uniform): waves 0-3: B+C; 4-5: U; 6-7: rank
  bool roleBC = tid < 256;
  int llB = tid >> 4, n4 = (tid & 15) * 4;
  int su = tid - 256, llU = su >> 3, d4u = (su & 7) * 4;
  int sq = tid - 384, llR = sq >> 3, r4 = (sq & 7) * 4;
  auto posf = [&](int l) {
    int lr = 1023 - l;
    return (k == 0) ? l
         : (k == 1) ? ((l & 31) * 32 + (l >> 5))
         : (k == 2) ? lr
                    : ((lr & 31) * 32 + (lr >> 5));
  };

  // stage chunk 0
  if (roleBC) {
    *(float4*)&Bsh[0][llB][n4] = *(const float4*)(sp + spB + (size_t)llB * 384 + n4);
    *(float4*)&Csh[0][llB][n4] = *(const float4*)(Cs + csB + (size_t)llB * 256 + n4);
  } else if (tid < 384) {
    *(float4*)&Ush[0][llU][d4u] = *(const float4*)(xa + xaB + (size_t)posf(llU) * DI_ + d4u);
  } else {
    *(float4*)&Rsh[0][llR][r4] = *(const float4*)(sp + spR + (size_t)llR * 384 + r4);
  }
  __syncthreads();
  {  // delta for chunk 0
    int ll = tid >> 5, dd = tid & 31;
    float acc = biasv;
    #pragma unroll
    for (int r = 0; r < 32; ++r) acc = fmaf(Rsh[0][ll][r], Wsh[r][dd], acc);
    DLsh[0][ll][dd] = (acc > 15.f) ? acc : log1pf(__expf(acc));
  }
  __syncthreads();

  int cur = 0;
  for (int c = 0; c < NCH; ++c) {
    float4 p0, p1;
    if (c < NCH - 1) {  // prefetch chunk c+1 into registers
      int lb = (c + 1) * CH;
      if (roleBC) {
        p0 = *(const float4*)(sp + spB + (size_t)(lb + llB) * 384 + n4);
        p1 = *(const float4*)(Cs + csB + (size_t)(lb + llB) * 256 + n4);
      } else if (tid < 384) {
        p0 = *(const float4*)(xa + xaB + (size_t)posf(lb + llU) * DI_ + d4u);
      } else {
        p0 = *(const float4*)(sp + spR + (size_t)(lb + llR) * 384 + r4);
      }
    }
    #pragma unroll
    for (int li = 0; li < CH; ++li) {
      float dlt = DLsh[cur][li][wd];
      float u = Ush[cur][li][wd];
      float du = dlt * u;
      float4 bq = *(const float4*)&Bsh[cur][li][ng * 4];
      float4 cq = *(const float4*)&Csh[cur][li][ng * 4];
      float bv[4] = {bq.x, bq.y, bq.z, bq.w};
      float cv[4] = {cq.x, cq.y, cq.z, cq.w};
      float yp = 0.f;
      #pragma unroll
      for (int j = 0; j < 4; ++j) {
        float e = __builtin_amdgcn_exp2f(dlt * a2[j]);
        h[j] = fmaf(e, h[j], du * bv[j]);
        yp = fmaf(h[j], cv[j], yp);
      }
      yp += __shfl_xor(yp, 4, 64);
      yp += __shfl_xor(yp, 8, 64);
      yp += __shfl_xor(yp, 16, 64);
      yp += __shfl_xor(yp, 32, 64);
      if (ng == 0) yl[li][wd] = fmaf(u, dsv, yp);
    }
    __syncthreads();  // chunk consumed; yl complete
    if (c < NCH - 1) {
      int nxt = cur ^ 1;
      if (roleBC) {
        *(float4*)&Bsh[nxt][llB][n4] = p0;
        *(float4*)&Csh[nxt][llB][n4] = p1;
      } else if (tid < 384) {
        *(float4*)&Ush[nxt][llU][d4u] = p0;
      } else {
        *(float4*)&Rsh[nxt][llR][r4] = p0;
      }
    }
    {  // y writeback (coalesced over d)
      int ll = tid >> 5, dd = tid & 31;
      ybuf[yB + (size_t)(c * CH + ll) * DI_ + dd] = yl[ll][dd];
    }
    __syncthreads();  // staged data + yl consumption visible
    if (c < NCH - 1) {  // delta for chunk c+1
      int nxt = cur ^ 1;
      int ll = tid >> 5, dd = tid & 31;
      float acc = biasv;
      #pragma unroll
      for (int r = 0; r < 32; ++r) acc = fmaf(Rsh[nxt][ll][r], Wsh[r][dd], acc);
      DLsh[nxt][ll][dd] = (acc > 15.f) ? acc : log1pf(__expf(acc));
    }
    __syncthreads();  // DLsh[nxt] visible for next iteration
    cur ^= 1;
  }
}

// ---------------- fuse: ygz = (sum_k yk) * z ----------------
__global__ __launch_bounds__(256) void fuse_ygz(
    const float* __restrict__ yk, const float* __restrict__ xz, float* __restrict__ ygz) {
  size_t i = (size_t)blockIdx.x * 256 + threadIdx.x;  // (b,l,d)
  size_t b = i >> 20, ld = i & ((1u << 20) - 1);
  float s = 0.f;
  #pragma unroll
  for (int k = 0; k < 4; ++k) s += yk[((size_t)(b * 4 + k) << 20) + ld];
  ygz[i] = s * xz[(i >> 10) * (2 * DI_) + DI_ + (i & (DI_ - 1))];
}

// ---------------- host ----------------
extern "C" void kernel_launch(void* const* d_in, const int* in_sizes, int n_in,
                              void* d_out, int out_size, void* d_ws, size_t ws_size,
                              hipStream_t stream) {
  (void)in_sizes; (void)n_in; (void)out_size; (void)ws_size;
  const float* content   = (const float*)d_in[0];
  const float* style     = (const float*)d_in[1];
  const float* norm1_w   = (const float*)d_in[2];
  const float* norm1_b   = (const float*)d_in[3];
  const float* in_proj_w = (const float*)d_in[4];
  const float* conv_w    = (const float*)d_in[5];
  const float* conv_b    = (const float*)d_in[6];
  const float* style_proj_w   = (const float*)d_in[7];
  const float* content_proj_w = (const float*)d_in[8];
  const float* dtw       = (const float*)d_in[9];
  const float* dtb       = (const float*)d_in[10];
  const float* A_logs    = (const float*)d_in[11];
  const float* Ds        = (const float*)d_in[12];
  const float* out_proj_w = (const float*)d_in[13];
  const float* norm2_w   = (const float*)d_in[14];
  const float* norm2_b   = (const float*)d_in[15];
  const float* mlp_w1    = (const float*)d_in[16];
  const float* mlp_b1    = (const float*)d_in[17];
  const float* mlp_w2    = (const float*)d_in[18];
  const float* mlp_b2    = (const float*)d_in[19];
  float* out = (float*)d_out;

  float* ws = (float*)d_ws;
  const size_t ROWS = (size_t)B_ * L_;  // 4096
  size_t o = 0;
  float* cn    = ws + o; o += ROWS * HID_;        // later reused as x1
  float* sn    = ws + o; o += ROWS * HID_;        // later reused as xn
  float* xz    = ws + o; o += ROWS * 2 * DI_;
  float* sp    = ws + o; o += ROWS * 384;
  float* xa    = ws + o; o += ROWS * DI_;
  float* csb   = ws + o; o += ROWS * 256;
  float* ybuf  = ws + o; o += (size_t)B_ * K_ * L_ * DI_;  // y; later reused as mlp hidden
  float* ygz   = ws + o; o += ROWS * DI_;
  unsigned short* wt = (unsigned short*)(ws + o);
  unsigned short* inpT = wt;                    // (2048,512)
  unsigned short* styT = inpT + 2048 * 512;     // (384,512)
  unsigned short* conT = styT + 384 * 512;      // (256,1024)
  unsigned short* outT = conT + 256 * 1024;     // (512,1024)
  unsigned short* w1T  = outT + 512 * 1024;     // (2048,512)
  unsigned short* w2T  = w1T + 2048 * 512;      // (512,2048)
  float* x1 = cn;
  float* xn = sn;
  float* hmid = ybuf;  // 4096x2048 fits

  // weight transpose+cast to bf16 (N,K)
  transpose_cast<<<dim3(2048 / 32, 512 / 32), 256, 0, stream>>>(in_proj_w, inpT, 512, 2048);
  transpose_cast<<<dim3(384 / 32, 512 / 32), 256, 0, stream>>>(style_proj_w, styT, 512, 384);
  transpose_cast<<<dim3(256 / 32, 1024 / 32), 256, 0, stream>>>(content_proj_w, conT, 1024, 256);
  transpose_cast<<<dim3(512 / 32, 1024 / 32), 256, 0, stream>>>(out_proj_w, outT, 1024, 512);
  transpose_cast<<<dim3(2048 / 32, 512 / 32), 256, 0, stream>>>(mlp_w1, w1T, 512, 2048);
  transpose_cast<<<dim3(512 / 32, 2048 / 32), 256, 0, stream>>>(mlp_w2, w2T, 2048, 512);

  // norm1 on content and style
  ln_kernel<<<ROWS / 4, 256, 0, stream>>>(content, cn, norm1_w, norm1_b);
  ln_kernel<<<ROWS / 4, 256, 0, stream>>>(style, sn, norm1_w, norm1_b);

  // xz = cn @ in_proj
  gemm_kernel<0><<<dim3(2048 / BN, ROWS / BM), 256, 0, stream>>>(
      cn, inpT, xz, ROWS, 2048, 512, nullptr, nullptr);
  // sp = sn @ style_proj
  gemm_kernel<0><<<dim3(384 / BN, ROWS / BM), 256, 0, stream>>>(
      sn, styT, sp, ROWS, 384, 512, nullptr, nullptr);
  // conv + silu -> xa
  conv_kernel<<<(ROWS * DI_) / 256, 256, 0, stream>>>(xz, conv_w, conv_b, xa);
  // Cs = xa @ content_proj
  gemm_kernel<0><<<dim3(256 / BN, ROWS / BM), 256, 0, stream>>>(
      xa, conT, csb, ROWS, 256, 1024, nullptr, nullptr);
  // selective scan with fused dt-projection -> ybuf
  scan_kernel<<<dim3(DI_ / 32, K_, B_), 512, 0, stream>>>(
      ybuf, xa, sp, csb, A_logs, Ds, dtw, dtb);
  // ygz = (sum_k y) * z
  fuse_ygz<<<(ROWS * DI_) / 256, 256, 0, stream>>>(ybuf, xz, ygz);
  // x1 = content + ygz @ out_proj
  gemm_kernel<1><<<dim3(512 / BN, ROWS / BM), 256, 0, stream>>>(
      ygz, outT, x1, ROWS, 512, 1024, nullptr, content);
  // norm2
  ln_kernel<<<ROWS / 4, 256, 0, stream>>>(x1, xn, norm2_w, norm2_b);
  // mlp
  gemm_kernel<2><<<dim3(2048 / BN, ROWS / BM), 256, 0, stream>>>(
      xn, w1T, hmid, ROWS, 2048, 512, mlp_b1, nullptr);
  gemm_kernel<3><<<dim3(512 / BN, ROWS / BM), 256, 0, stream>>>(
      hmid, w2T, out, ROWS, 512, 2048, mlp_b2, x1);
}

// Round 4
// 675.083 us; speedup vs baseline: 1.0715x; 1.0715x over previous
//
#include <hip/hip_runtime.h>

// ---------------- constants ----------------
#define B_ 4
#define Hh_ 32
#define Ww_ 32
#define L_ 1024
#define HID_ 512
#define DI_ 1024
#define N_ 64
#define R_ 32
#define K_ 4
#define MLP_ 2048

typedef __bf16 bf16x8 __attribute__((ext_vector_type(8)));
typedef float f32x4 __attribute__((ext_vector_type(4)));

__device__ __forceinline__ unsigned short f2bf(float f) {
  unsigned int u = __builtin_bit_cast(unsigned int, f);
  return (unsigned short)((u + 0x7FFFu + ((u >> 16) & 1u)) >> 16);
}
__device__ __forceinline__ float bf2f(unsigned short h) {
  return __builtin_bit_cast(float, (unsigned int)h << 16);
}

// ---------------- transpose + cast weights: src (K,N) f32 -> dst (N,K) bf16 ----------------
__global__ __launch_bounds__(256) void transpose_cast(
    const float* __restrict__ src, unsigned short* __restrict__ dst, int K, int N) {
  __shared__ float t[32][33];
  int nb = blockIdx.x * 32, kb = blockIdx.y * 32;
  int tx = threadIdx.x & 31, ty = threadIdx.x >> 5;
  for (int r = ty; r < 32; r += 8) t[r][tx] = src[(size_t)(kb + r) * N + nb + tx];
  __syncthreads();
  for (int r = ty; r < 32; r += 8) dst[(size_t)(nb + r) * K + kb + tx] = f2bf(t[tx][r]);
}

// ---------------- LayerNorm over 512, wave per row ----------------
__global__ __launch_bounds__(256) void ln_kernel(
    const float* __restrict__ in, float* __restrict__ out,
    const float* __restrict__ w, const float* __restrict__ bb) {
  int row = blockIdx.x * 4 + (threadIdx.x >> 6);
  int lane = threadIdx.x & 63;
  const float* p = in + (size_t)row * HID_;
  float4 v0 = *(const float4*)(p + lane * 4);
  float4 v1 = *(const float4*)(p + 256 + lane * 4);
  float s = v0.x + v0.y + v0.z + v0.w + v1.x + v1.y + v1.z + v1.w;
  float q = v0.x * v0.x + v0.y * v0.y + v0.z * v0.z + v0.w * v0.w +
            v1.x * v1.x + v1.y * v1.y + v1.z * v1.z + v1.w * v1.w;
  #pragma unroll
  for (int m = 1; m < 64; m <<= 1) { s += __shfl_xor(s, m, 64); q += __shfl_xor(q, m, 64); }
  float mean = s * (1.f / 512.f);
  float var = q * (1.f / 512.f) - mean * mean;
  float rstd = rsqrtf(var + 1e-5f);
  float4 w0 = *(const float4*)(w + lane * 4);
  float4 w1 = *(const float4*)(w + 256 + lane * 4);
  float4 b0 = *(const float4*)(bb + lane * 4);
  float4 b1 = *(const float4*)(bb + 256 + lane * 4);
  float* o = out + (size_t)row * HID_;
  float4 r0, r1;
  r0.x = (v0.x - mean) * rstd * w0.x + b0.x;
  r0.y = (v0.y - mean) * rstd * w0.y + b0.y;
  r0.z = (v0.z - mean) * rstd * w0.z + b0.z;
  r0.w = (v0.w - mean) * rstd * w0.w + b0.w;
  r1.x = (v1.x - mean) * rstd * w1.x + b1.x;
  r1.y = (v1.y - mean) * rstd * w1.y + b1.y;
  r1.z = (v1.z - mean) * rstd * w1.z + b1.z;
  r1.w = (v1.w - mean) * rstd * w1.w + b1.w;
  *(float4*)(o + lane * 4) = r0;
  *(float4*)(o + 256 + lane * 4) = r1;
}

// ---------------- MFMA GEMM 128x128: A (M,K) f32, BT (N,K) bf16, C (M,N) f32 ----------------
// EPI: 0 = plain, 1 = +resid, 2 = +bias then exact gelu, 3 = +bias +resid
#define BM 128
#define BN 128
#define BK 32
#define LST 40  // LDS row stride in bf16 units

template <int EPI>
__global__ __launch_bounds__(256) void gemm_kernel(
    const float* __restrict__ A, const unsigned short* __restrict__ BT,
    float* __restrict__ C, int M, int N, int K,
    const float* __restrict__ bias, const float* __restrict__ resid) {
  __shared__ __align__(16) unsigned short As[BM * LST];
  __shared__ __align__(16) unsigned short Bs[BN * LST];
  int tid = threadIdx.x;
  int lane = tid & 63, wv = tid >> 6;
  int wm = wv >> 1, wn = wv & 1;
  int m0 = blockIdx.y * BM, n0 = blockIdx.x * BN;
  f32x4 acc[4][4] = {};
  int sr = tid >> 3, sc = (tid & 7) * 4;
  int kk = (lane >> 4) * 8;
  int rA = wm * 64 + (lane & 15);
  int rB = wn * 64 + (lane & 15);
  for (int k0 = 0; k0 < K; k0 += BK) {
    __syncthreads();
    #pragma unroll
    for (int p = 0; p < 4; ++p) {
      int r = sr + p * 32;
      float4 av = *(const float4*)(A + (size_t)(m0 + r) * K + k0 + sc);
      unsigned int lo = (unsigned int)f2bf(av.x) | ((unsigned int)f2bf(av.y) << 16);
      unsigned int hi = (unsigned int)f2bf(av.z) | ((unsigned int)f2bf(av.w) << 16);
      *(uint2*)&As[r * LST + sc] = make_uint2(lo, hi);
      uint2 bv = *(const uint2*)(BT + (size_t)(n0 + r) * K + k0 + sc);
      *(uint2*)&Bs[r * LST + sc] = bv;
    }
    __syncthreads();
    bf16x8 fa[4], fb[4];
    #pragma unroll
    for (int i = 0; i < 4; ++i) {
      fa[i] = *(const bf16x8*)&As[(rA + i * 16) * LST + kk];
      fb[i] = *(const bf16x8*)&Bs[(rB + i * 16) * LST + kk];
    }
    #pragma unroll
    for (int i = 0; i < 4; ++i)
      #pragma unroll
      for (int j = 0; j < 4; ++j)
        acc[i][j] = __builtin_amdgcn_mfma_f32_16x16x32_bf16(fa[i], fb[j], acc[i][j], 0, 0, 0);
  }
  int crow0 = m0 + wm * 64 + (lane >> 4) * 4, ccol0 = n0 + wn * 64 + (lane & 15);
  #pragma unroll
  for (int i = 0; i < 4; ++i) {
    #pragma unroll
    for (int j = 0; j < 4; ++j) {
      int col = ccol0 + j * 16;
      #pragma unroll
      for (int r = 0; r < 4; ++r) {
        int row = crow0 + i * 16 + r;
        float v = acc[i][j][r];
        if (EPI == 1) v += resid[(size_t)row * N + col];
        if (EPI == 2) { v += bias[col]; v = 0.5f * v * (1.f + erff(v * 0.70710678f)); }
        if (EPI == 3) v += bias[col] + resid[(size_t)row * N + col];
        C[(size_t)row * N + col] = v;
      }
    }
  }
}

// ---------------- MFMA GEMM 64x128 (for small-N GEMMs; more blocks) ----------------
template <int EPI>
__global__ __launch_bounds__(256) void gemm64_kernel(
    const float* __restrict__ A, const unsigned short* __restrict__ BT,
    float* __restrict__ C, int M, int N, int K,
    const float* __restrict__ bias, const float* __restrict__ resid) {
  __shared__ __align__(16) unsigned short As[64 * LST];
  __shared__ __align__(16) unsigned short Bs[128 * LST];
  int tid = threadIdx.x;
  int lane = tid & 63, wv = tid >> 6;
  int wm = wv >> 1, wn = wv & 1;
  int m0 = blockIdx.y * 64, n0 = blockIdx.x * BN;
  f32x4 acc[2][4] = {};
  int sr = tid >> 3, sc = (tid & 7) * 4;
  int kk = (lane >> 4) * 8;
  int rA = wm * 32 + (lane & 15);
  int rB = wn * 64 + (lane & 15);
  for (int k0 = 0; k0 < K; k0 += BK) {
    __syncthreads();
    #pragma unroll
    for (int p = 0; p < 2; ++p) {
      int r = sr + p * 32;
      float4 av = *(const float4*)(A + (size_t)(m0 + r) * K + k0 + sc);
      unsigned int lo = (unsigned int)f2bf(av.x) | ((unsigned int)f2bf(av.y) << 16);
      unsigned int hi = (unsigned int)f2bf(av.z) | ((unsigned int)f2bf(av.w) << 16);
      *(uint2*)&As[r * LST + sc] = make_uint2(lo, hi);
    }
    #pragma unroll
    for (int p = 0; p < 4; ++p) {
      int r = sr + p * 32;
      uint2 bv = *(const uint2*)(BT + (size_t)(n0 + r) * K + k0 + sc);
      *(uint2*)&Bs[r * LST + sc] = bv;
    }
    __syncthreads();
    bf16x8 fa[2], fb[4];
    #pragma unroll
    for (int i = 0; i < 2; ++i) fa[i] = *(const bf16x8*)&As[(rA + i * 16) * LST + kk];
    #pragma unroll
    for (int j = 0; j < 4; ++j) fb[j] = *(const bf16x8*)&Bs[(rB + j * 16) * LST + kk];
    #pragma unroll
    for (int i = 0; i < 2; ++i)
      #pragma unroll
      for (int j = 0; j < 4; ++j)
        acc[i][j] = __builtin_amdgcn_mfma_f32_16x16x32_bf16(fa[i], fb[j], acc[i][j], 0, 0, 0);
  }
  int crow0 = m0 + wm * 32 + (lane >> 4) * 4, ccol0 = n0 + wn * 64 + (lane & 15);
  #pragma unroll
  for (int i = 0; i < 2; ++i) {
    #pragma unroll
    for (int j = 0; j < 4; ++j) {
      int col = ccol0 + j * 16;
      #pragma unroll
      for (int r = 0; r < 4; ++r) {
        int row = crow0 + i * 16 + r;
        float v = acc[i][j][r];
        if (EPI == 1) v += resid[(size_t)row * N + col];
        if (EPI == 2) { v += bias[col]; v = 0.5f * v * (1.f + erff(v * 0.70710678f)); }
        if (EPI == 3) v += bias[col] + resid[(size_t)row * N + col];
        C[(size_t)row * N + col] = v;
      }
    }
  }
}

// ---------------- depthwise 3x3 conv + bias + SiLU (channels-last) ----------------
__global__ __launch_bounds__(256) void conv_kernel(
    const float* __restrict__ xz, const float* __restrict__ cw,
    const float* __restrict__ cb, float* __restrict__ xa) {
  int idx = blockIdx.x * 256 + threadIdx.x;  // (b,l,d), d fastest
  int d = idx & (DI_ - 1);
  int l = (idx >> 10) & (L_ - 1);
  int b = idx >> 20;
  int hh = l >> 5, ww = l & 31;
  float acc = cb[d];
  #pragma unroll
  for (int dh = -1; dh <= 1; ++dh) {
    int y = hh + dh;
    if ((unsigned)y >= 32u) continue;
    #pragma unroll
    for (int dw = -1; dw <= 1; ++dw) {
      int x = ww + dw;
      if ((unsigned)x >= 32u) continue;
      acc = fmaf(xz[((size_t)b * L_ + y * 32 + x) * (2 * DI_) + d],
                 cw[d * 9 + (dh + 1) * 3 + (dw + 1)], acc);
    }
  }
  float sv = acc / (1.f + __expf(-acc));
  xa[idx] = sv;
}

// ---------------- dt projection + softplus -> delta [b][k][l][d] (bf16) ----------------
__global__ __launch_bounds__(256) void delta_kernel(
    const float* __restrict__ sp, const float* __restrict__ dtw,
    const float* __restrict__ dtb, unsigned short* __restrict__ delta) {
  int bk = blockIdx.x;
  int b = bk >> 2, k = bk & 3;
  int dc = blockIdx.y * 256;
  int l0 = blockIdx.z * 128;
  __shared__ float wl[32 * 257];
  __shared__ float rl[128 * 32];
  int tid = threadIdx.x;
  for (int i = tid; i < 256 * 32; i += 256) {
    int dl = i >> 5, r = i & 31;
    wl[r * 257 + dl] = dtw[((size_t)k * DI_ + dc + dl) * R_ + r];
  }
  for (int i = tid; i < 128 * 32; i += 256) {
    int ll = i >> 5, r = i & 31;
    rl[ll * 32 + r] = sp[((size_t)b * L_ + l0 + ll) * 384 + k * R_ + r];
  }
  __syncthreads();
  float bias = dtb[k * DI_ + dc + tid];
  for (int ll = 0; ll < 128; ++ll) {
    float acc = bias;
    #pragma unroll
    for (int r = 0; r < 32; ++r)
      acc = fmaf(rl[ll * 32 + r], wl[r * 257 + tid], acc);
    float dlt = (acc > 15.f) ? acc : log1pf(__expf(acc));
    delta[(((size_t)(b * 4 + k) * L_) + l0 + ll) * DI_ + dc + tid] = f2bf(dlt);
  }
}

// ---------------- selective scan ----------------
// Lane layout: dg = lane&3 (4 d per wave), ng = lane>>2 (16 n-groups of 4 n).
// Block: 512 threads = 8 waves = 32 d. Grid: (DI/32, K, B) = 512 blocks -> 4 waves/SIMD.
// r2-style pipeline: register prefetch, exactly 2 syncthreads per chunk.
#define CH 16
#define NCH (L_ / CH)
__global__ __launch_bounds__(512) void scan_kernel(
    unsigned short* __restrict__ ybuf, const float* __restrict__ xa,
    const float* __restrict__ sp, const float* __restrict__ Cs,
    const unsigned short* __restrict__ dltb,
    const float* __restrict__ A_logs, const float* __restrict__ Ds) {
  int dblk = blockIdx.x;  // 32 blocks of 32 d's
  int k = blockIdx.y, b = blockIdx.z;
  int tid = threadIdx.x, lane = tid & 63, wv = tid >> 6;
  int dg = lane & 3, ng = lane >> 2;
  int wd = wv * 4 + dg;                // d within block's 32
  int gd = k * DI_ + dblk * 32 + wd;
  float a2[4], h[4];
  #pragma unroll
  for (int j = 0; j < 4; ++j) {
    a2[j] = -__expf(A_logs[(size_t)gd * N_ + ng * 4 + j]) * 1.44269504f;
    h[j] = 0.f;
  }
  float dsv = Ds[gd];

  __shared__ float Bsh[2][CH][64], Csh[2][CH][64];
  __shared__ float Ush[2][CH][32], DLsh[2][CH][32];
  __shared__ unsigned short ylh[CH][32];

  const size_t spB = (size_t)b * L_ * 384 + 128 + k * 64;  // B part of style proj
  const size_t csB = (size_t)b * L_ * 256 + k * 64;
  const size_t dlB = ((size_t)(b * 4 + k) * L_) * DI_ + dblk * 32;
  const size_t yB  = dlB;
  const size_t xaB = (size_t)b * L_ * DI_ + dblk * 32;

  // staging roles:
  //   tid in [0,256):   B row llB, cols n4    (also tid<128: U row llU, cols d4)
  //   tid in [256,512): C row llC, cols n4    (tid in [128,256): DL row llD, cols q4)
  int llB = (tid & 255) >> 4, n4 = (tid & 15) * 4;
  int llU = tid >> 3, d4 = (tid & 7) * 4;          // valid for tid<128
  int llD = (tid - 128) >> 3, q4 = (tid & 7) * 4;  // valid for tid in [128,256)
  bool isB = tid < 256;
  bool isU = tid < 128;
  bool isD = (tid >= 128) && (tid < 256);
  auto posf = [&](int l) {
    int lr = 1023 - l;
    return (k == 0) ? l
         : (k == 1) ? ((l & 31) * 32 + (l >> 5))
         : (k == 2) ? lr
                    : ((lr & 31) * 32 + (lr >> 5));
  };

  // stage chunk 0 directly
  if (isB) {
    *(float4*)&Bsh[0][llB][n4] = *(const float4*)(sp + spB + (size_t)llB * 384 + n4);
  } else {
    *(float4*)&Csh[0][llB][n4] = *(const float4*)(Cs + csB + (size_t)llB * 256 + n4);
  }
  if (isU) {
    *(float4*)&Ush[0][llU][d4] = *(const float4*)(xa + xaB + (size_t)posf(llU) * DI_ + d4);
  } else if (isD) {
    ushort4 dv = *(const ushort4*)(dltb + dlB + (size_t)llD * DI_ + q4);
    DLsh[0][llD][q4 + 0] = bf2f(dv.x);
    DLsh[0][llD][q4 + 1] = bf2f(dv.y);
    DLsh[0][llD][q4 + 2] = bf2f(dv.z);
    DLsh[0][llD][q4 + 3] = bf2f(dv.w);
  }
  __syncthreads();

  int cur = 0;
  for (int c = 0; c < NCH; ++c) {
    float4 pBC;
    float4 pU;
    ushort4 pD;
    if (c < NCH - 1) {  // prefetch chunk c+1 into registers
      int lb = (c + 1) * CH;
      if (isB) pBC = *(const float4*)(sp + spB + (size_t)(lb + llB) * 384 + n4);
      else     pBC = *(const float4*)(Cs + csB + (size_t)(lb + llB) * 256 + n4);
      if (isU) pU = *(const float4*)(xa + xaB + (size_t)posf(lb + llU) * DI_ + d4);
      else if (isD) pD = *(const ushort4*)(dltb + dlB + (size_t)(lb + llD) * DI_ + q4);
    }
    #pragma unroll
    for (int li = 0; li < CH; ++li) {
      float dlt = DLsh[cur][li][wd];
      float u = Ush[cur][li][wd];
      float du = dlt * u;
      float4 bq = *(const float4*)&Bsh[cur][li][ng * 4];
      float4 cq = *(const float4*)&Csh[cur][li][ng * 4];
      float yp = 0.f;
      {
        float e = __builtin_amdgcn_exp2f(dlt * a2[0]);
        h[0] = fmaf(e, h[0], du * bq.x); yp = fmaf(h[0], cq.x, yp);
      }
      {
        float e = __builtin_amdgcn_exp2f(dlt * a2[1]);
        h[1] = fmaf(e, h[1], du * bq.y); yp = fmaf(h[1], cq.y, yp);
      }
      {
        float e = __builtin_amdgcn_exp2f(dlt * a2[2]);
        h[2] = fmaf(e, h[2], du * bq.z); yp = fmaf(h[2], cq.z, yp);
      }
      {
        float e = __builtin_amdgcn_exp2f(dlt * a2[3]);
        h[3] = fmaf(e, h[3], du * bq.w); yp = fmaf(h[3], cq.w, yp);
      }
      yp += __shfl_xor(yp, 4, 64);
      yp += __shfl_xor(yp, 8, 64);
      yp += __shfl_xor(yp, 16, 64);
      yp += __shfl_xor(yp, 32, 64);
      if (ng == 0) ylh[li][wd] = f2bf(fmaf(u, dsv, yp));
    }
    __syncthreads();  // chunk consumed; ylh complete
    if (c < NCH - 1) {
      int nxt = cur ^ 1;
      if (isB) *(float4*)&Bsh[nxt][llB][n4] = pBC;
      else     *(float4*)&Csh[nxt][llB][n4] = pBC;
      if (isU) *(float4*)&Ush[nxt][llU][d4] = pU;
      else if (isD) {
        DLsh[nxt][llD][q4 + 0] = bf2f(pD.x);
        DLsh[nxt][llD][q4 + 1] = bf2f(pD.y);
        DLsh[nxt][llD][q4 + 2] = bf2f(pD.z);
        DLsh[nxt][llD][q4 + 3] = bf2f(pD.w);
      }
    }
    if (isU) {  // y writeback: 16 rows x 32 d bf16, 8B per thread
      int ll = llU, q = (tid & 7) * 4;
      ushort4 yv = *(const ushort4*)&ylh[ll][q];
      *(ushort4*)(ybuf + yB + (size_t)(c * CH + ll) * DI_ + q) = yv;
    }
    __syncthreads();  // staging + ylh consumption visible
    cur ^= 1;
  }
}

// ---------------- fuse: ygz = (sum_k yk) * z  (yk bf16) ----------------
__global__ __launch_bounds__(256) void fuse_ygz(
    const unsigned short* __restrict__ yk, const float* __restrict__ xz,
    float* __restrict__ ygz) {
  size_t i = ((size_t)blockIdx.x * 256 + threadIdx.x) * 8;  // 8 d per thread
  size_t b = i >> 20, ld = i & ((1u << 20) - 1);
  float acc[8] = {};
  #pragma unroll
  for (int k = 0; k < 4; ++k) {
    uint4 v = *(const uint4*)(yk + ((size_t)(b * 4 + k) << 20) + ld);
    unsigned int w[4] = {v.x, v.y, v.z, v.w};
    #pragma unroll
    for (int t = 0; t < 4; ++t) {
      acc[t * 2 + 0] += __builtin_bit_cast(float, w[t] << 16);
      acc[t * 2 + 1] += __builtin_bit_cast(float, w[t] & 0xFFFF0000u);
    }
  }
  const float* zp = xz + (i >> 10) * (2 * DI_) + DI_ + (i & (DI_ - 1));
  float4 z0 = *(const float4*)zp;
  float4 z1 = *(const float4*)(zp + 4);
  float4 o0, o1;
  o0.x = acc[0] * z0.x; o0.y = acc[1] * z0.y; o0.z = acc[2] * z0.z; o0.w = acc[3] * z0.w;
  o1.x = acc[4] * z1.x; o1.y = acc[5] * z1.y; o1.z = acc[6] * z1.z; o1.w = acc[7] * z1.w;
  *(float4*)(ygz + i) = o0;
  *(float4*)(ygz + i + 4) = o1;
}

// ---------------- host ----------------
extern "C" void kernel_launch(void* const* d_in, const int* in_sizes, int n_in,
                              void* d_out, int out_size, void* d_ws, size_t ws_size,
                              hipStream_t stream) {
  (void)in_sizes; (void)n_in; (void)out_size; (void)ws_size;
  const float* content   = (const float*)d_in[0];
  const float* style     = (const float*)d_in[1];
  const float* norm1_w   = (const float*)d_in[2];
  const float* norm1_b   = (const float*)d_in[3];
  const float* in_proj_w = (const float*)d_in[4];
  const float* conv_w    = (const float*)d_in[5];
  const float* conv_b    = (const float*)d_in[6];
  const float* style_proj_w   = (const float*)d_in[7];
  const float* content_proj_w = (const float*)d_in[8];
  const float* dtw       = (const float*)d_in[9];
  const float* dtb       = (const float*)d_in[10];
  const float* A_logs    = (const float*)d_in[11];
  const float* Ds        = (const float*)d_in[12];
  const float* out_proj_w = (const float*)d_in[13];
  const float* norm2_w   = (const float*)d_in[14];
  const float* norm2_b   = (const float*)d_in[15];
  const float* mlp_w1    = (const float*)d_in[16];
  const float* mlp_b1    = (const float*)d_in[17];
  const float* mlp_w2    = (const float*)d_in[18];
  const float* mlp_b2    = (const float*)d_in[19];
  float* out = (float*)d_out;

  float* ws = (float*)d_ws;
  const size_t ROWS = (size_t)B_ * L_;  // 4096
  const size_t SCAN_ELEMS = (size_t)B_ * K_ * L_ * DI_;  // 16.78M
  size_t o = 0;
  float* cn    = ws + o; o += ROWS * HID_;        // reused as x1
  float* sn    = ws + o; o += ROWS * HID_;        // reused as xn
  float* xz    = ws + o; o += ROWS * 2 * DI_;
  float* sp    = ws + o; o += ROWS * 384;
  float* xa    = ws + o; o += ROWS * DI_;
  float* csb   = ws + o; o += ROWS * 256;
  unsigned short* dltb = (unsigned short*)(ws + o); o += SCAN_ELEMS / 2;  // bf16 delta
  unsigned short* ybuf = (unsigned short*)(ws + o); o += SCAN_ELEMS / 2;  // bf16 y; reused as hmid
  float* ygz   = ws + o; o += ROWS * DI_;
  unsigned short* wt = (unsigned short*)(ws + o);
  unsigned short* inpT = wt;                    // (2048,512)
  unsigned short* styT = inpT + 2048 * 512;     // (384,512)
  unsigned short* conT = styT + 384 * 512;      // (256,1024)
  unsigned short* outT = conT + 256 * 1024;     // (512,1024)
  unsigned short* w1T  = outT + 512 * 1024;     // (2048,512)
  unsigned short* w2T  = w1T + 2048 * 512;      // (512,2048)
  float* x1 = cn;
  float* xn = sn;
  float* hmid = (float*)ybuf;  // 4096x2048 f32 == 33.5 MB == ybuf region exactly

  // weight transpose+cast to bf16 (N,K)
  transpose_cast<<<dim3(2048 / 32, 512 / 32), 256, 0, stream>>>(in_proj_w, inpT, 512, 2048);
  transpose_cast<<<dim3(384 / 32, 512 / 32), 256, 0, stream>>>(style_proj_w, styT, 512, 384);
  transpose_cast<<<dim3(256 / 32, 1024 / 32), 256, 0, stream>>>(content_proj_w, conT, 1024, 256);
  transpose_cast<<<dim3(512 / 32, 1024 / 32), 256, 0, stream>>>(out_proj_w, outT, 1024, 512);
  transpose_cast<<<dim3(2048 / 32, 512 / 32), 256, 0, stream>>>(mlp_w1, w1T, 512, 2048);
  transpose_cast<<<dim3(512 / 32, 2048 / 32), 256, 0, stream>>>(mlp_w2, w2T, 2048, 512);

  // norm1 on content and style
  ln_kernel<<<ROWS / 4, 256, 0, stream>>>(content, cn, norm1_w, norm1_b);
  ln_kernel<<<ROWS / 4, 256, 0, stream>>>(style, sn, norm1_w, norm1_b);

  // xz = cn @ in_proj  (N=2048: 128x128 tiles, 512 blocks)
  gemm_kernel<0><<<dim3(2048 / BN, ROWS / BM), 256, 0, stream>>>(
      cn, inpT, xz, ROWS, 2048, 512, nullptr, nullptr);
  // sp = sn @ style_proj  (N=384: 64-row tiles, 192 blocks)
  gemm64_kernel<0><<<dim3(384 / BN, ROWS / 64), 256, 0, stream>>>(
      sn, styT, sp, ROWS, 384, 512, nullptr, nullptr);
  // conv + silu -> xa
  conv_kernel<<<(ROWS * DI_) / 256, 256, 0, stream>>>(xz, conv_w, conv_b, xa);
  // Cs = xa @ content_proj  (N=256, 128 blocks)
  gemm64_kernel<0><<<dim3(256 / BN, ROWS / 64), 256, 0, stream>>>(
      xa, conT, csb, ROWS, 256, 1024, nullptr, nullptr);
  // delta = softplus(rank @ dtw + bias) -> bf16
  delta_kernel<<<dim3(B_ * K_, DI_ / 256, L_ / 128), 256, 0, stream>>>(sp, dtw, dtb, dltb);
  // selective scan -> ybuf (bf16)
  scan_kernel<<<dim3(DI_ / 32, K_, B_), 512, 0, stream>>>(
      ybuf, xa, sp, csb, dltb, A_logs, Ds);
  // ygz = (sum_k y) * z
  fuse_ygz<<<(ROWS * DI_) / (256 * 8), 256, 0, stream>>>(ybuf, xz, ygz);
  // x1 = content + ygz @ out_proj  (N=512, 256 blocks)
  gemm64_kernel<1><<<dim3(512 / BN, ROWS / 64), 256, 0, stream>>>(
      ygz, outT, x1, ROWS, 512, 1024, nullptr, content);
  // norm2
  ln_kernel<<<ROWS / 4, 256, 0, stream>>>(x1, xn, norm2_w, norm2_b);
  // mlp
  gemm_kernel<2><<<dim3(2048 / BN, ROWS / BM), 256, 0, stream>>>(
      xn, w1T, hmid, ROWS, 2048, 512, mlp_b1, nullptr);
  gemm64_kernel<3><<<dim3(512 / BN, ROWS / 64), 256, 0, stream>>>(
      hmid, w2T, out, ROWS, 512, 2048, mlp_b2, x1);
}

// Round 5
// 666.699 us; speedup vs baseline: 1.0850x; 1.0126x over previous
//
#include <hip/hip_runtime.h>

// ---------------- constants ----------------
#define B_ 4
#define Hh_ 32
#define Ww_ 32
#define L_ 1024
#define HID_ 512
#define DI_ 1024
#define N_ 64
#define R_ 32
#define K_ 4
#define MLP_ 2048

typedef __bf16 bf16x8 __attribute__((ext_vector_type(8)));
typedef float f32x4 __attribute__((ext_vector_type(4)));

__device__ __forceinline__ unsigned short f2bf(float f) {
  unsigned int u = __builtin_bit_cast(unsigned int, f);
  return (unsigned short)((u + 0x7FFFu + ((u >> 16) & 1u)) >> 16);
}
__device__ __forceinline__ float bf2f(unsigned short h) {
  return __builtin_bit_cast(float, (unsigned int)h << 16);
}

// quad_perm DPP add: x + x[lane ^ (1 or 2)] on the VALU pipe (no DS)
template <int CTRL>
__device__ __forceinline__ float dpp_qadd(float x) {
  int i = __builtin_bit_cast(int, x);
  int j = __builtin_amdgcn_update_dpp(i, i, CTRL, 0xF, 0xF, false);
  return x + __builtin_bit_cast(float, j);
}

// ---------------- transpose + cast weights: src (K,N) f32 -> dst (N,K) bf16 ----------------
__global__ __launch_bounds__(256) void transpose_cast(
    const float* __restrict__ src, unsigned short* __restrict__ dst, int K, int N) {
  __shared__ float t[32][33];
  int nb = blockIdx.x * 32, kb = blockIdx.y * 32;
  int tx = threadIdx.x & 31, ty = threadIdx.x >> 5;
  for (int r = ty; r < 32; r += 8) t[r][tx] = src[(size_t)(kb + r) * N + nb + tx];
  __syncthreads();
  for (int r = ty; r < 32; r += 8) dst[(size_t)(nb + r) * K + kb + tx] = f2bf(t[tx][r]);
}

// ---------------- LayerNorm over 512, wave per row ----------------
__global__ __launch_bounds__(256) void ln_kernel(
    const float* __restrict__ in, float* __restrict__ out,
    const float* __restrict__ w, const float* __restrict__ bb) {
  int row = blockIdx.x * 4 + (threadIdx.x >> 6);
  int lane = threadIdx.x & 63;
  const float* p = in + (size_t)row * HID_;
  float4 v0 = *(const float4*)(p + lane * 4);
  float4 v1 = *(const float4*)(p + 256 + lane * 4);
  float s = v0.x + v0.y + v0.z + v0.w + v1.x + v1.y + v1.z + v1.w;
  float q = v0.x * v0.x + v0.y * v0.y + v0.z * v0.z + v0.w * v0.w +
            v1.x * v1.x + v1.y * v1.y + v1.z * v1.z + v1.w * v1.w;
  #pragma unroll
  for (int m = 1; m < 64; m <<= 1) { s += __shfl_xor(s, m, 64); q += __shfl_xor(q, m, 64); }
  float mean = s * (1.f / 512.f);
  float var = q * (1.f / 512.f) - mean * mean;
  float rstd = rsqrtf(var + 1e-5f);
  float4 w0 = *(const float4*)(w + lane * 4);
  float4 w1 = *(const float4*)(w + 256 + lane * 4);
  float4 b0 = *(const float4*)(bb + lane * 4);
  float4 b1 = *(const float4*)(bb + 256 + lane * 4);
  float* o = out + (size_t)row * HID_;
  float4 r0, r1;
  r0.x = (v0.x - mean) * rstd * w0.x + b0.x;
  r0.y = (v0.y - mean) * rstd * w0.y + b0.y;
  r0.z = (v0.z - mean) * rstd * w0.z + b0.z;
  r0.w = (v0.w - mean) * rstd * w0.w + b0.w;
  r1.x = (v1.x - mean) * rstd * w1.x + b1.x;
  r1.y = (v1.y - mean) * rstd * w1.y + b1.y;
  r1.z = (v1.z - mean) * rstd * w1.z + b1.z;
  r1.w = (v1.w - mean) * rstd * w1.w + b1.w;
  *(float4*)(o + lane * 4) = r0;
  *(float4*)(o + 256 + lane * 4) = r1;
}

// ---------------- MFMA GEMM 128x128: A (M,K) f32, BT (N,K) bf16, C (M,N) f32 ----------------
// EPI: 0 = plain, 1 = +resid, 2 = +bias then exact gelu, 3 = +bias +resid
#define BM 128
#define BN 128
#define BK 32
#define LST 40  // LDS row stride in bf16 units

template <int EPI>
__global__ __launch_bounds__(256) void gemm_kernel(
    const float* __restrict__ A, const unsigned short* __restrict__ BT,
    float* __restrict__ C, int M, int N, int K,
    const float* __restrict__ bias, const float* __restrict__ resid) {
  __shared__ __align__(16) unsigned short As[BM * LST];
  __shared__ __align__(16) unsigned short Bs[BN * LST];
  int tid = threadIdx.x;
  int lane = tid & 63, wv = tid >> 6;
  int wm = wv >> 1, wn = wv & 1;
  int m0 = blockIdx.y * BM, n0 = blockIdx.x * BN;
  f32x4 acc[4][4] = {};
  int sr = tid >> 3, sc = (tid & 7) * 4;
  int kk = (lane >> 4) * 8;
  int rA = wm * 64 + (lane & 15);
  int rB = wn * 64 + (lane & 15);
  for (int k0 = 0; k0 < K; k0 += BK) {
    __syncthreads();
    #pragma unroll
    for (int p = 0; p < 4; ++p) {
      int r = sr + p * 32;
      float4 av = *(const float4*)(A + (size_t)(m0 + r) * K + k0 + sc);
      unsigned int lo = (unsigned int)f2bf(av.x) | ((unsigned int)f2bf(av.y) << 16);
      unsigned int hi = (unsigned int)f2bf(av.z) | ((unsigned int)f2bf(av.w) << 16);
      *(uint2*)&As[r * LST + sc] = make_uint2(lo, hi);
      uint2 bv = *(const uint2*)(BT + (size_t)(n0 + r) * K + k0 + sc);
      *(uint2*)&Bs[r * LST + sc] = bv;
    }
    __syncthreads();
    bf16x8 fa[4], fb[4];
    #pragma unroll
    for (int i = 0; i < 4; ++i) {
      fa[i] = *(const bf16x8*)&As[(rA + i * 16) * LST + kk];
      fb[i] = *(const bf16x8*)&Bs[(rB + i * 16) * LST + kk];
    }
    #pragma unroll
    for (int i = 0; i < 4; ++i)
      #pragma unroll
      for (int j = 0; j < 4; ++j)
        acc[i][j] = __builtin_amdgcn_mfma_f32_16x16x32_bf16(fa[i], fb[j], acc[i][j], 0, 0, 0);
  }
  int crow0 = m0 + wm * 64 + (lane >> 4) * 4, ccol0 = n0 + wn * 64 + (lane & 15);
  #pragma unroll
  for (int i = 0; i < 4; ++i) {
    #pragma unroll
    for (int j = 0; j < 4; ++j) {
      int col = ccol0 + j * 16;
      #pragma unroll
      for (int r = 0; r < 4; ++r) {
        int row = crow0 + i * 16 + r;
        float v = acc[i][j][r];
        if (EPI == 1) v += resid[(size_t)row * N + col];
        if (EPI == 2) { v += bias[col]; v = 0.5f * v * (1.f + erff(v * 0.70710678f)); }
        if (EPI == 3) v += bias[col] + resid[(size_t)row * N + col];
        C[(size_t)row * N + col] = v;
      }
    }
  }
}

// ---------------- MFMA GEMM 64x128 (for small-N GEMMs; more blocks) ----------------
template <int EPI>
__global__ __launch_bounds__(256) void gemm64_kernel(
    const float* __restrict__ A, const unsigned short* __restrict__ BT,
    float* __restrict__ C, int M, int N, int K,
    const float* __restrict__ bias, const float* __restrict__ resid) {
  __shared__ __align__(16) unsigned short As[64 * LST];
  __shared__ __align__(16) unsigned short Bs[128 * LST];
  int tid = threadIdx.x;
  int lane = tid & 63, wv = tid >> 6;
  int wm = wv >> 1, wn = wv & 1;
  int m0 = blockIdx.y * 64, n0 = blockIdx.x * BN;
  f32x4 acc[2][4] = {};
  int sr = tid >> 3, sc = (tid & 7) * 4;
  int kk = (lane >> 4) * 8;
  int rA = wm * 32 + (lane & 15);
  int rB = wn * 64 + (lane & 15);
  for (int k0 = 0; k0 < K; k0 += BK) {
    __syncthreads();
    #pragma unroll
    for (int p = 0; p < 2; ++p) {
      int r = sr + p * 32;
      float4 av = *(const float4*)(A + (size_t)(m0 + r) * K + k0 + sc);
      unsigned int lo = (unsigned int)f2bf(av.x) | ((unsigned int)f2bf(av.y) << 16);
      unsigned int hi = (unsigned int)f2bf(av.z) | ((unsigned int)f2bf(av.w) << 16);
      *(uint2*)&As[r * LST + sc] = make_uint2(lo, hi);
    }
    #pragma unroll
    for (int p = 0; p < 4; ++p) {
      int r = sr + p * 32;
      uint2 bv = *(const uint2*)(BT + (size_t)(n0 + r) * K + k0 + sc);
      *(uint2*)&Bs[r * LST + sc] = bv;
    }
    __syncthreads();
    bf16x8 fa[2], fb[4];
    #pragma unroll
    for (int i = 0; i < 2; ++i) fa[i] = *(const bf16x8*)&As[(rA + i * 16) * LST + kk];
    #pragma unroll
    for (int j = 0; j < 4; ++j) fb[j] = *(const bf16x8*)&Bs[(rB + j * 16) * LST + kk];
    #pragma unroll
    for (int i = 0; i < 2; ++i)
      #pragma unroll
      for (int j = 0; j < 4; ++j)
        acc[i][j] = __builtin_amdgcn_mfma_f32_16x16x32_bf16(fa[i], fb[j], acc[i][j], 0, 0, 0);
  }
  int crow0 = m0 + wm * 32 + (lane >> 4) * 4, ccol0 = n0 + wn * 64 + (lane & 15);
  #pragma unroll
  for (int i = 0; i < 2; ++i) {
    #pragma unroll
    for (int j = 0; j < 4; ++j) {
      int col = ccol0 + j * 16;
      #pragma unroll
      for (int r = 0; r < 4; ++r) {
        int row = crow0 + i * 16 + r;
        float v = acc[i][j][r];
        if (EPI == 1) v += resid[(size_t)row * N + col];
        if (EPI == 2) { v += bias[col]; v = 0.5f * v * (1.f + erff(v * 0.70710678f)); }
        if (EPI == 3) v += bias[col] + resid[(size_t)row * N + col];
        C[(size_t)row * N + col] = v;
      }
    }
  }
}

// ---------------- depthwise 3x3 conv + bias + SiLU (channels-last) ----------------
__global__ __launch_bounds__(256) void conv_kernel(
    const float* __restrict__ xz, const float* __restrict__ cw,
    const float* __restrict__ cb, float* __restrict__ xa) {
  int idx = blockIdx.x * 256 + threadIdx.x;  // (b,l,d), d fastest
  int d = idx & (DI_ - 1);
  int l = (idx >> 10) & (L_ - 1);
  int b = idx >> 20;
  int hh = l >> 5, ww = l & 31;
  float acc = cb[d];
  #pragma unroll
  for (int dh = -1; dh <= 1; ++dh) {
    int y = hh + dh;
    if ((unsigned)y >= 32u) continue;
    #pragma unroll
    for (int dw = -1; dw <= 1; ++dw) {
      int x = ww + dw;
      if ((unsigned)x >= 32u) continue;
      acc = fmaf(xz[((size_t)b * L_ + y * 32 + x) * (2 * DI_) + d],
                 cw[d * 9 + (dh + 1) * 3 + (dw + 1)], acc);
    }
  }
  float sv = acc / (1.f + __expf(-acc));
  xa[idx] = sv;
}

// ---------------- dt projection + softplus -> delta [b][k][l][d] (bf16) ----------------
__global__ __launch_bounds__(256) void delta_kernel(
    const float* __restrict__ sp, const float* __restrict__ dtw,
    const float* __restrict__ dtb, unsigned short* __restrict__ delta) {
  int bk = blockIdx.x;
  int b = bk >> 2, k = bk & 3;
  int dc = blockIdx.y * 256;
  int l0 = blockIdx.z * 128;
  __shared__ float wl[32 * 257];
  __shared__ float rl[128 * 32];
  int tid = threadIdx.x;
  for (int i = tid; i < 256 * 32; i += 256) {
    int dl = i >> 5, r = i & 31;
    wl[r * 257 + dl] = dtw[((size_t)k * DI_ + dc + dl) * R_ + r];
  }
  for (int i = tid; i < 128 * 32; i += 256) {
    int ll = i >> 5, r = i & 31;
    rl[ll * 32 + r] = sp[((size_t)b * L_ + l0 + ll) * 384 + k * R_ + r];
  }
  __syncthreads();
  float bias = dtb[k * DI_ + dc + tid];
  for (int ll = 0; ll < 128; ++ll) {
    float acc = bias;
    #pragma unroll
    for (int r = 0; r < 32; ++r)
      acc = fmaf(rl[ll * 32 + r], wl[r * 257 + tid], acc);
    float dlt = (acc > 15.f) ? acc : log1pf(__expf(acc));
    delta[(((size_t)(b * 4 + k) * L_) + l0 + ll) * DI_ + dc + tid] = f2bf(dlt);
  }
}

// ---------------- selective scan (DS-minimized) ----------------
// lane = dg*8 + ng: dg = lane>>3 (8 d per wave), ng = lane&7 (owns n = ng*8..ng*8+7).
// Block: 512 thr = 8 waves = 64 d. Grid (DI/64, K, B) = 256 blocks, 8 waves/CU.
// Per step per wave DS: 1x b64 (dlt,u) + 1x b128 B(bf16) + 1x b128 C(bf16) + 1 ds_swizzle.
// n-reduce: xor1+xor2 via DPP quad_perm (VALU), xor4 via ds_swizzle. y -> global (vmem).
#define CH 16
#define NCH (L_ / CH)
__global__ __launch_bounds__(512) void scan_kernel(
    unsigned short* __restrict__ ybuf, const float* __restrict__ xa,
    const float* __restrict__ sp, const float* __restrict__ Cs,
    const unsigned short* __restrict__ dltb,
    const float* __restrict__ A_logs, const float* __restrict__ Ds) {
  int dblk = blockIdx.x;  // 16 blocks of 64 d's
  int k = blockIdx.y, b = blockIdx.z;
  int tid = threadIdx.x, lane = tid & 63, wv = tid >> 6;
  int dg = lane >> 3, ng = lane & 7;
  int wd = wv * 8 + dg;                // d within block's 64
  int gd = k * DI_ + dblk * 64 + wd;
  float a2[8], h[8];
  #pragma unroll
  for (int j = 0; j < 8; ++j) {
    a2[j] = -__expf(A_logs[(size_t)gd * N_ + ng * 8 + j]) * 1.44269504f;
    h[j] = 0.f;
  }
  float dsv = Ds[gd];

  __shared__ unsigned short Bsh[2][CH][64];   // bf16 [li][n]
  __shared__ unsigned short Csh[2][CH][64];   // bf16 [li][n]
  __shared__ float DLU[2][CH][64][2];         // f32 (dlt,u) pairs [li][d]

  const size_t spB = (size_t)b * L_ * 384 + 128 + k * 64;  // B part of style proj
  const size_t csB = (size_t)b * L_ * 256 + k * 64;
  const size_t dlB = ((size_t)(b * 4 + k) * L_) * DI_ + dblk * 64;
  const size_t yB  = dlB;
  const size_t xaB = (size_t)b * L_ * DI_ + dblk * 64;

  // staging roles: tid<256: B+C (liB row, 4 n); tid>=256: U+DL (liU row, 4 d)
  int liB = tid >> 4, n4 = (tid & 15) * 4;          // tid<256
  int su = tid - 256, liU = su >> 4, d4 = (su & 15) * 4;  // tid>=256
  bool isBC = tid < 256;
  auto posf = [&](int l) {
    int lr = 1023 - l;
    return (k == 0) ? l
         : (k == 1) ? ((l & 31) * 32 + (l >> 5))
         : (k == 2) ? lr
                    : ((lr & 31) * 32 + (lr >> 5));
  };

  // stage chunk 0
  if (isBC) {
    float4 pB = *(const float4*)(sp + spB + (size_t)liB * 384 + n4);
    float4 pC = *(const float4*)(Cs + csB + (size_t)liB * 256 + n4);
    ushort4 wB = {f2bf(pB.x), f2bf(pB.y), f2bf(pB.z), f2bf(pB.w)};
    ushort4 wC = {f2bf(pC.x), f2bf(pC.y), f2bf(pC.z), f2bf(pC.w)};
    *(ushort4*)&Bsh[0][liB][n4] = wB;
    *(ushort4*)&Csh[0][liB][n4] = wC;
  } else {
    float4 pU = *(const float4*)(xa + xaB + (size_t)posf(liU) * DI_ + d4);
    ushort4 pD = *(const ushort4*)(dltb + dlB + (size_t)liU * DI_ + d4);
    float4 w0 = {bf2f(pD.x), pU.x, bf2f(pD.y), pU.y};
    float4 w1 = {bf2f(pD.z), pU.z, bf2f(pD.w), pU.w};
    *(float4*)&DLU[0][liU][d4][0] = w0;
    *(float4*)&DLU[0][liU][d4 + 2][0] = w1;
  }
  __syncthreads();

  int cur = 0;
  for (int c = 0; c < NCH; ++c) {
    float4 pB, pC, pU;
    ushort4 pD;
    if (c < NCH - 1) {  // prefetch chunk c+1 into registers
      int lb = (c + 1) * CH;
      if (isBC) {
        pB = *(const float4*)(sp + spB + (size_t)(lb + liB) * 384 + n4);
        pC = *(const float4*)(Cs + csB + (size_t)(lb + liB) * 256 + n4);
      } else {
        pU = *(const float4*)(xa + xaB + (size_t)posf(lb + liU) * DI_ + d4);
        pD = *(const ushort4*)(dltb + dlB + (size_t)(lb + liU) * DI_ + d4);
      }
    }
    #pragma unroll
    for (int li = 0; li < CH; ++li) {
      float2 du2 = *(const float2*)&DLU[cur][li][wd][0];
      float dlt = du2.x, u = du2.y;
      float du = dlt * u;
      uint4 bq = *(const uint4*)&Bsh[cur][li][ng * 8];
      uint4 cq = *(const uint4*)&Csh[cur][li][ng * 8];
      float bv[8], cv[8];
      bv[0] = __builtin_bit_cast(float, bq.x << 16);
      bv[1] = __builtin_bit_cast(float, bq.x & 0xFFFF0000u);
      bv[2] = __builtin_bit_cast(float, bq.y << 16);
      bv[3] = __builtin_bit_cast(float, bq.y & 0xFFFF0000u);
      bv[4] = __builtin_bit_cast(float, bq.z << 16);
      bv[5] = __builtin_bit_cast(float, bq.z & 0xFFFF0000u);
      bv[6] = __builtin_bit_cast(float, bq.w << 16);
      bv[7] = __builtin_bit_cast(float, bq.w & 0xFFFF0000u);
      cv[0] = __builtin_bit_cast(float, cq.x << 16);
      cv[1] = __builtin_bit_cast(float, cq.x & 0xFFFF0000u);
      cv[2] = __builtin_bit_cast(float, cq.y << 16);
      cv[3] = __builtin_bit_cast(float, cq.y & 0xFFFF0000u);
      cv[4] = __builtin_bit_cast(float, cq.z << 16);
      cv[5] = __builtin_bit_cast(float, cq.z & 0xFFFF0000u);
      cv[6] = __builtin_bit_cast(float, cq.w << 16);
      cv[7] = __builtin_bit_cast(float, cq.w & 0xFFFF0000u);
      float yp = 0.f;
      #pragma unroll
      for (int j = 0; j < 8; ++j) {
        float e = __builtin_amdgcn_exp2f(dlt * a2[j]);
        h[j] = fmaf(e, h[j], du * bv[j]);
        yp = fmaf(h[j], cv[j], yp);
      }
      // n-reduce across 8 ng lanes: xor1, xor2 on VALU (DPP), xor4 on DS
      yp = dpp_qadd<0xB1>(yp);  // quad_perm [1,0,3,2]
      yp = dpp_qadd<0x4E>(yp);  // quad_perm [2,3,0,1]
      {
        int i = __builtin_bit_cast(int, yp);
        int j = __builtin_amdgcn_ds_swizzle(i, 0x101F);  // xor4
        yp += __builtin_bit_cast(float, j);
      }
      if (ng == 0) {  // 8 lanes store 8 consecutive bf16 d's (16B, one vmem op)
        ybuf[yB + (size_t)(c * CH + li) * DI_ + wd] = f2bf(fmaf(u, dsv, yp));
      }
    }
    __syncthreads();  // chunk consumed
    if (c < NCH - 1) {
      int nxt = cur ^ 1;
      if (isBC) {
        ushort4 wB = {f2bf(pB.x), f2bf(pB.y), f2bf(pB.z), f2bf(pB.w)};
        ushort4 wC = {f2bf(pC.x), f2bf(pC.y), f2bf(pC.z), f2bf(pC.w)};
        *(ushort4*)&Bsh[nxt][liB][n4] = wB;
        *(ushort4*)&Csh[nxt][liB][n4] = wC;
      } else {
        float4 w0 = {bf2f(pD.x), pU.x, bf2f(pD.y), pU.y};
        float4 w1 = {bf2f(pD.z), pU.z, bf2f(pD.w), pU.w};
        *(float4*)&DLU[nxt][liU][d4][0] = w0;
        *(float4*)&DLU[nxt][liU][d4 + 2][0] = w1;
      }
    }
    __syncthreads();  // staging visible
    cur ^= 1;
  }
}

// ---------------- fuse: ygz = (sum_k yk) * z  (yk bf16) ----------------
__global__ __launch_bounds__(256) void fuse_ygz(
    const unsigned short* __restrict__ yk, const float* __restrict__ xz,
    float* __restrict__ ygz) {
  size_t i = ((size_t)blockIdx.x * 256 + threadIdx.x) * 8;  // 8 d per thread
  size_t b = i >> 20, ld = i & ((1u << 20) - 1);
  float acc[8] = {};
  #pragma unroll
  for (int k = 0; k < 4; ++k) {
    uint4 v = *(const uint4*)(yk + ((size_t)(b * 4 + k) << 20) + ld);
    unsigned int w[4] = {v.x, v.y, v.z, v.w};
    #pragma unroll
    for (int t = 0; t < 4; ++t) {
      acc[t * 2 + 0] += __builtin_bit_cast(float, w[t] << 16);
      acc[t * 2 + 1] += __builtin_bit_cast(float, w[t] & 0xFFFF0000u);
    }
  }
  const float* zp = xz + (i >> 10) * (2 * DI_) + DI_ + (i & (DI_ - 1));
  float4 z0 = *(const float4*)zp;
  float4 z1 = *(const float4*)(zp + 4);
  float4 o0, o1;
  o0.x = acc[0] * z0.x; o0.y = acc[1] * z0.y; o0.z = acc[2] * z0.z; o0.w = acc[3] * z0.w;
  o1.x = acc[4] * z1.x; o1.y = acc[5] * z1.y; o1.z = acc[6] * z1.z; o1.w = acc[7] * z1.w;
  *(float4*)(ygz + i) = o0;
  *(float4*)(ygz + i + 4) = o1;
}

// ---------------- host ----------------
extern "C" void kernel_launch(void* const* d_in, const int* in_sizes, int n_in,
                              void* d_out, int out_size, void* d_ws, size_t ws_size,
                              hipStream_t stream) {
  (void)in_sizes; (void)n_in; (void)out_size; (void)ws_size;
  const float* content   = (const float*)d_in[0];
  const float* style     = (const float*)d_in[1];
  const float* norm1_w   = (const float*)d_in[2];
  const float* norm1_b   = (const float*)d_in[3];
  const float* in_proj_w = (const float*)d_in[4];
  const float* conv_w    = (const float*)d_in[5];
  const float* conv_b    = (const float*)d_in[6];
  const float* style_proj_w   = (const float*)d_in[7];
  const float* content_proj_w = (const float*)d_in[8];
  const float* dtw       = (const float*)d_in[9];
  const float* dtb       = (const float*)d_in[10];
  const float* A_logs    = (const float*)d_in[11];
  const float* Ds        = (const float*)d_in[12];
  const float* out_proj_w = (const float*)d_in[13];
  const float* norm2_w   = (const float*)d_in[14];
  const float* norm2_b   = (const float*)d_in[15];
  const float* mlp_w1    = (const float*)d_in[16];
  const float* mlp_b1    = (const float*)d_in[17];
  const float* mlp_w2    = (const float*)d_in[18];
  const float* mlp_b2    = (const float*)d_in[19];
  float* out = (float*)d_out;

  float* ws = (float*)d_ws;
  const size_t ROWS = (size_t)B_ * L_;  // 4096
  const size_t SCAN_ELEMS = (size_t)B_ * K_ * L_ * DI_;  // 16.78M
  size_t o = 0;
  float* cn    = ws + o; o += ROWS * HID_;        // reused as x1
  float* sn    = ws + o; o += ROWS * HID_;        // reused as xn
  float* xz    = ws + o; o += ROWS * 2 * DI_;
  float* sp    = ws + o; o += ROWS * 384;
  float* xa    = ws + o; o += ROWS * DI_;
  float* csb   = ws + o; o += ROWS * 256;
  unsigned short* dltb = (unsigned short*)(ws + o); o += SCAN_ELEMS / 2;  // bf16 delta
  unsigned short* ybuf = (unsigned short*)(ws + o); o += SCAN_ELEMS / 2;  // bf16 y; reused as hmid
  float* ygz   = ws + o; o += ROWS * DI_;
  unsigned short* wt = (unsigned short*)(ws + o);
  unsigned short* inpT = wt;                    // (2048,512)
  unsigned short* styT = inpT + 2048 * 512;     // (384,512)
  unsigned short* conT = styT + 384 * 512;      // (256,1024)
  unsigned short* outT = conT + 256 * 1024;     // (512,1024)
  unsigned short* w1T  = outT + 512 * 1024;     // (2048,512)
  unsigned short* w2T  = w1T + 2048 * 512;      // (512,2048)
  float* x1 = cn;
  float* xn = sn;
  float* hmid = (float*)ybuf;  // 4096x2048 f32 fits in ybuf region

  // weight transpose+cast to bf16 (N,K)
  transpose_cast<<<dim3(2048 / 32, 512 / 32), 256, 0, stream>>>(in_proj_w, inpT, 512, 2048);
  transpose_cast<<<dim3(384 / 32, 512 / 32), 256, 0, stream>>>(style_proj_w, styT, 512, 384);
  transpose_cast<<<dim3(256 / 32, 1024 / 32), 256, 0, stream>>>(content_proj_w, conT, 1024, 256);
  transpose_cast<<<dim3(512 / 32, 1024 / 32), 256, 0, stream>>>(out_proj_w, outT, 1024, 512);
  transpose_cast<<<dim3(2048 / 32, 512 / 32), 256, 0, stream>>>(mlp_w1, w1T, 512, 2048);
  transpose_cast<<<dim3(512 / 32, 2048 / 32), 256, 0, stream>>>(mlp_w2, w2T, 2048, 512);

  // norm1 on content and style
  ln_kernel<<<ROWS / 4, 256, 0, stream>>>(content, cn, norm1_w, norm1_b);
  ln_kernel<<<ROWS / 4, 256, 0, stream>>>(style, sn, norm1_w, norm1_b);

  // xz = cn @ in_proj
  gemm_kernel<0><<<dim3(2048 / BN, ROWS / BM), 256, 0, stream>>>(
      cn, inpT, xz, ROWS, 2048, 512, nullptr, nullptr);
  // sp = sn @ style_proj
  gemm64_kernel<0><<<dim3(384 / BN, ROWS / 64), 256, 0, stream>>>(
      sn, styT, sp, ROWS, 384, 512, nullptr, nullptr);
  // conv + silu -> xa
  conv_kernel<<<(ROWS * DI_) / 256, 256, 0, stream>>>(xz, conv_w, conv_b, xa);
  // Cs = xa @ content_proj
  gemm64_kernel<0><<<dim3(256 / BN, ROWS / 64), 256, 0, stream>>>(
      xa, conT, csb, ROWS, 256, 1024, nullptr, nullptr);
  // delta = softplus(rank @ dtw + bias) -> bf16
  delta_kernel<<<dim3(B_ * K_, DI_ / 256, L_ / 128), 256, 0, stream>>>(sp, dtw, dtb, dltb);
  // selective scan -> ybuf (bf16)
  scan_kernel<<<dim3(DI_ / 64, K_, B_), 512, 0, stream>>>(
      ybuf, xa, sp, csb, dltb, A_logs, Ds);
  // ygz = (sum_k y) * z
  fuse_ygz<<<(ROWS * DI_) / (256 * 8), 256, 0, stream>>>(ybuf, xz, ygz);
  // x1 = content + ygz @ out_proj
  gemm64_kernel<1><<<dim3(512 / BN, ROWS / 64), 256, 0, stream>>>(
      ygz, outT, x1, ROWS, 512, 1024, nullptr, content);
  // norm2
  ln_kernel<<<ROWS / 4, 256, 0, stream>>>(x1, xn, norm2_w, norm2_b);
  // mlp
  gemm_kernel<2><<<dim3(2048 / BN, ROWS / BM), 256, 0, stream>>>(
      xn, w1T, hmid, ROWS, 2048, 512, mlp_b1, nullptr);
  gemm64_kernel<3><<<dim3(512 / BN, ROWS / 64), 256, 0, stream>>>(
      hmid, w2T, out, ROWS, 512, 2048, mlp_b2, x1);
}